// Round 17
// baseline (86.363 us; speedup 1.0000x reference)
//
#include <hip/hip_runtime.h>
#include <math.h>

// PointWarping: B=4, C=3, N=8192 fp32. Exact 3-NN via spatial grid + IDW warp.
//
// 5 dispatches:
//  k_zero  : zero counts + scanst
//  k_count : bin DB points (pos1+flow1), atomic counts
//  k_scan  : one-kernel exclusive scan (wave-parallel decoupled lookback)
//            + re-zero counts for scatter ranks
//  k_scat  : DB -> packed csr float4 (512 KB, L2-resident)
//  k_query : 32 lanes/query, lane owns ONE (dz,dy) CSR column; EXACT u64 keys
//            (d2_bits<<32 | idx — register-pair construction, free);
//            5-step butterfly merge; INLINE wave-coop brute fallback (ballot).
//
// R15 lesson: truncated keys flip neighbor identity (absmax 0.107) — selection
// must preserve full d2 ordering. u64 keys restore absmax 0.0 (R6-R14 proven).
//
// Exactness: cells h=0.22 on [-3.3,3.3]^3 (clamped). Any DB point >=3 cells
// away in some axis is > 2h=0.44 away, so 3rd-best d2 <= 0.44^2*0.999 proves
// the top-3 lies in the 5x5x5 block; else the wave brute-scans all 8192 points
// (also out-of-range queries). Keys are exact u64 (d2_bits<<32|idx):
// fp32-exact, (d2,idx)-lex == top_k tie-break, independent of CSR atomic order.

#define BB 4
#define NN 8192
#define BBNN (BB * NN)            // 32768
#define NC 30
#define NCELLS (NC * NC * NC)     // 27000
#define NCT (BB * NCELLS)         // 108000
#define GRID_R 3.3f
#define GRID_INVH (1.0f / 0.22f)
#define D3_THR (0.44f * 0.44f * 0.999f)
#define EPB 1024
#define SB 106                    // ceil(NCT/EPB)
#define NZ4 ((NCT + 108) / 4)     // counts + scanst (pad 108)
#define ST_PART 0x40000000u
#define ST_DONE 0x80000000u
#define ST_VAL 0x3FFFFFFFu

typedef unsigned long long u64;

__device__ __forceinline__ int cell_of(float x) {
  int c = (int)floorf((x + GRID_R) * GRID_INVH);
  return min(max(c, 0), NC - 1);
}

__device__ __forceinline__ void merge3(u64& a0, u64& a1, u64& a2,
                                       u64 b0, u64 b1, u64 b2) {
  const u64 lo0 = a0 < b0 ? a0 : b0;
  const u64 hi0 = a0 < b0 ? b0 : a0;
  const u64 lo1 = a1 < b1 ? a1 : b1;
  const u64 lo2 = a2 < b2 ? a2 : b2;
  const u64 o1 = hi0 < lo1 ? hi0 : lo1;
  const u64 t = hi0 < lo1 ? lo1 : hi0;
  a0 = lo0;
  a1 = o1;
  a2 = t < lo2 ? t : lo2;
}

__device__ __forceinline__ void insert3(u64& s0, u64& s1, u64& s2, u64 key) {
  const bool c0 = key < s0;
  const bool c1 = key < s1;
  const bool c2 = key < s2;
  s2 = c1 ? s1 : (c2 ? key : s2);
  s1 = c0 ? s0 : (c1 ? key : s1);
  s0 = c0 ? key : s0;
}

__device__ __forceinline__ void cand1(const float4& a, float qx, float qy,
                                      float qz, u64& s0, u64& s1, u64& s2) {
  const float dx = a.x - qx, dy = a.y - qy, dz = a.z - qz;
  const float d2 = fmaf(dx, dx, fmaf(dy, dy, dz * dz));
  insert3(s0, s1, s2,
          ((u64)__float_as_uint(d2) << 32) | (unsigned)__float_as_uint(a.w));
}

// IDW epilogue for one query (indices from low words of s0..s2)
__device__ __forceinline__ void idw_out(int b, int qn, float qx, float qy,
                                        float qz, u64 s0, u64 s1, u64 s2,
                                        const float* __restrict__ P1,
                                        const float* __restrict__ F1,
                                        float* __restrict__ out) {
  const int idxs[3] = {(int)(unsigned)s0 & (NN - 1),
                       (int)(unsigned)s1 & (NN - 1),
                       (int)(unsigned)s2 & (NN - 1)};
  float w[3], gfx[3], gfy[3], gfz[3];
  float wsumv = 0.0f;
#pragma unroll
  for (int r = 0; r < 3; ++r) {
    const int idx = idxs[r];
    const float fx = F1[idx], fy = F1[NN + idx], fz = F1[2 * NN + idx];
    const float kx = P1[idx] + fx;
    const float ky = P1[NN + idx] + fy;
    const float kz = P1[2 * NN + idx] + fz;
    const float dx = kx - qx, dy = ky - qy, dz = kz - qz;
    float d = sqrtf(dx * dx + dy * dy + dz * dz);
    d = fmaxf(d, 1e-10f);
    const float inv = 1.0f / d;
    w[r] = inv; wsumv += inv;
    gfx[r] = fx; gfy[r] = fy; gfz[r] = fz;
  }
  const float invw = 1.0f / wsumv;
  float ox = 0.0f, oy = 0.0f, oz = 0.0f;
#pragma unroll
  for (int r = 0; r < 3; ++r) {
    const float ww = w[r] * invw;
    ox = fmaf(ww, gfx[r], ox);
    oy = fmaf(ww, gfy[r], oy);
    oz = fmaf(ww, gfz[r], oz);
  }
  ox = qx - ox; oy = qy - oy; oz = qz - oz;
  ox = fminf(fmaxf(ox, -10.0f), 10.0f);
  oy = fminf(fmaxf(oy, -10.0f), 10.0f);
  oz = fminf(fmaxf(oz, -10.0f), 10.0f);
  float* o = out + (size_t)b * 3 * NN;
  o[qn] = ox;
  o[NN + qn] = oy;
  o[2 * NN + qn] = oz;
}

__global__ __launch_bounds__(256) void k_zero(int4* __restrict__ p) {
  const int i = blockIdx.x * 256 + threadIdx.x;
  if (i < NZ4) p[i] = make_int4(0, 0, 0, 0);
}

__global__ __launch_bounds__(256) void k_count(const float* __restrict__ p1,
                                               const float* __restrict__ f1,
                                               int* __restrict__ counts) {
  const int gid = blockIdx.x * 256 + threadIdx.x;  // 0..32767
  const int b = gid >> 13, n = gid & (NN - 1);
  const float* P = p1 + (size_t)b * 3 * NN;
  const float* F = f1 + (size_t)b * 3 * NN;
  const float x = P[n] + F[n];
  const float y = P[NN + n] + F[NN + n];
  const float z = P[2 * NN + n] + F[2 * NN + n];
  const int cid = (cell_of(z) * NC + cell_of(y)) * NC + cell_of(x);
  atomicAdd(&counts[b * NCELLS + cid], 1);
}

// one-kernel exclusive scan with wave-parallel decoupled lookback (R14-proven)
__global__ __launch_bounds__(256) void k_scan(int* __restrict__ counts,
                                              int* __restrict__ offs,
                                              unsigned* __restrict__ scanst) {
  __shared__ int wsums[4];
  __shared__ int sbase;
  const int tid = threadIdx.x, lane = tid & 63, wav = tid >> 6;
  const int bid = blockIdx.x;
  const int c = bid * EPB + tid * 4;
  int4 v = make_int4(0, 0, 0, 0);
  if (c < NCT) {
    v = *reinterpret_cast<const int4*>(counts + c);
    *reinterpret_cast<int4*>(counts + c) = make_int4(0, 0, 0, 0);  // rank reset
  }
  const int sum4 = v.x + v.y + v.z + v.w;
  int incl = sum4;
  for (int off = 1; off < 64; off <<= 1) {
    const int t = __shfl_up(incl, off, 64);
    incl += (lane >= off) ? t : 0;
  }
  if (lane == 63) wsums[wav] = incl;
  __syncthreads();
  int wbase = 0;
#pragma unroll
  for (int w = 0; w < 4; ++w) wbase += (w < wav) ? wsums[w] : 0;
  const int btot = wsums[0] + wsums[1] + wsums[2] + wsums[3];

  if (wav == 0) {
    if (lane == 0) atomicExch(&scanst[bid], ST_PART | (unsigned)btot);
    int base = 0;
    int j0 = bid;
    while (j0 > 0) {
      const int j = j0 - 64 + lane;
      unsigned s;
      if (j >= 0) {
        do { s = atomicAdd(&scanst[j], 0u); } while (s == 0u);
      } else {
        s = ST_DONE;
      }
      const u64 dball = __ballot((s & ST_DONE) != 0);
      int val;
      if (dball) {
        const int hi = 63 - __clzll(dball);
        val = (lane >= hi) ? (int)(s & ST_VAL) : 0;
      } else {
        val = (int)(s & ST_VAL);
      }
      for (int off = 32; off >= 1; off >>= 1) val += __shfl_down(val, off, 64);
      base += __shfl(val, 0, 64);
      if (dball) break;
      j0 -= 64;
    }
    if (lane == 0) {
      atomicExch(&scanst[bid], ST_DONE | (unsigned)(base + btot));
      sbase = base;
    }
  }
  __syncthreads();
  const int excl = sbase + wbase + incl - sum4;
  if (c < NCT) {
    int4 e;
    e.x = excl;
    e.y = excl + v.x;
    e.z = e.y + v.y;
    e.w = e.z + v.z;
    *reinterpret_cast<int4*>(offs + c) = e;
  }
  if (bid == SB - 1 && tid == 0) offs[NCT] = BBNN;
}

__global__ __launch_bounds__(256) void k_scat(const float* __restrict__ p1,
                                              const float* __restrict__ f1,
                                              int* __restrict__ counts,
                                              const int* __restrict__ offs,
                                              float4* __restrict__ csr) {
  const int gid = blockIdx.x * 256 + threadIdx.x;
  const int b = gid >> 13, n = gid & (NN - 1);
  const float* P = p1 + (size_t)b * 3 * NN;
  const float* F = f1 + (size_t)b * 3 * NN;
  const float x = P[n] + F[n];
  const float y = P[NN + n] + F[NN + n];
  const float z = P[2 * NN + n] + F[2 * NN + n];
  const int cid = (cell_of(z) * NC + cell_of(y)) * NC + cell_of(x);
  const int g = b * NCELLS + cid;
  const int rank = atomicAdd(&counts[g], 1);
  csr[offs[g] + rank] = make_float4(x, y, z, __int_as_float(n));
}

// scan one contiguous CSR run with 4-wide load batching
__device__ __forceinline__ void scan_col(int st, int en,
                                         const float4* __restrict__ csr,
                                         float qx, float qy, float qz,
                                         u64& s0, u64& s1, u64& s2) {
  int j = st;
  for (; j + 4 <= en; j += 4) {
    const float4 a = csr[j];
    const float4 b = csr[j + 1];
    const float4 c = csr[j + 2];
    const float4 d = csr[j + 3];
    cand1(a, qx, qy, qz, s0, s1, s2);
    cand1(b, qx, qy, qz, s0, s1, s2);
    cand1(c, qx, qy, qz, s0, s1, s2);
    cand1(d, qx, qy, qz, s0, s1, s2);
  }
  for (; j < en; ++j) {
    const float4 a = csr[j];
    cand1(a, qx, qy, qz, s0, s1, s2);
  }
}

// 32 lanes/query (2 queries/wave); lane r (r<25) owns one (dz,dy) CSR column.
// Inline wave-cooperative brute fallback for failed/OOR queries.
__global__ __launch_bounds__(256) void k_query(const float* __restrict__ p1,
                                               const float* __restrict__ p2,
                                               const float* __restrict__ f1,
                                               const int* __restrict__ offs,
                                               const float4* __restrict__ csr,
                                               float* __restrict__ out) {
  const int tid = threadIdx.x;
  const int lane = tid & 63;
  const int gtid = blockIdx.x * 256 + tid;   // 0..1048575
  const int qid = gtid >> 5;
  const int r = gtid & 31;
  const int b = qid >> 13;
  const int qn = qid & (NN - 1);
  const float* P1 = p1 + (size_t)b * 3 * NN;
  const float* P2 = p2 + (size_t)b * 3 * NN;
  const float* F1 = f1 + (size_t)b * 3 * NN;

  const float qx = P2[qn], qy = P2[NN + qn], qz = P2[2 * NN + qn];
  const bool oor = !(fabsf(qx) < GRID_R && fabsf(qy) < GRID_R && fabsf(qz) < GRID_R);

  u64 s0 = ~0ULL, s1 = ~0ULL, s2 = ~0ULL;

  if (!oor && r < 25) {
    const int qcx = cell_of(qx), qcy = cell_of(qy), qcz = cell_of(qz);
    const int gxl = max(qcx - 2, 0);
    const int span = min(qcx + 2, NC - 1) - gxl + 1;
    const int dzi = (r * 205) >> 10;  // r/5 for r<=24
    const int gz = qcz + dzi - 2;
    const int gy = qcy + (r - dzi * 5) - 2;
    if (((unsigned)gz < NC) & ((unsigned)gy < NC)) {
      const int ia = b * NCELLS + (gz * NC + gy) * NC + gxl;
      const int st = offs[ia];
      const int en = offs[ia + span];
      scan_col(st, en, csr, qx, qy, qz, s0, s1, s2);
    }
  }

  // merge the 32 partial triples (5 butterfly steps); all lanes get result
#pragma unroll
  for (int mask = 1; mask <= 16; mask <<= 1) {
    const u64 b0 = __shfl_xor(s0, mask, 64);
    const u64 b1 = __shfl_xor(s1, mask, 64);
    const u64 b2 = __shfl_xor(s2, mask, 64);
    merge3(s0, s1, s2, b0, b1, b2);
  }

  // sentinel/empty -> NaN bits -> comparison false -> fallback (NaN-safe)
  const float d3 = __uint_as_float((unsigned)(s2 >> 32));
  const bool ok = !oor && (d3 <= D3_THR);

  if (r == 0 && ok) idw_out(b, qn, qx, qy, qz, s0, s1, s2, P1, F1, out);

  // inline wave-cooperative brute fallback (queries at lanes 0 and 32)
  const u64 bal = __ballot((r == 0) && !ok);
  if (bal != 0) {
#pragma unroll
    for (int q = 0; q < 2; ++q) {
      if (!((bal >> (32 * q)) & 1ULL)) continue;
      const int fqn = __shfl(qn, 32 * q, 64);
      const float fqx = __shfl(qx, 32 * q, 64);
      const float fqy = __shfl(qy, 32 * q, 64);
      const float fqz = __shfl(qz, 32 * q, 64);
      u64 a0 = ~0ULL, a1 = ~0ULL, a2 = ~0ULL;
      for (int t = 0; t < NN / 64; ++t) {
        const int g = t * 64 + lane;
        const float x = P1[g] + F1[g];
        const float y = P1[NN + g] + F1[NN + g];
        const float z = P1[2 * NN + g] + F1[2 * NN + g];
        const float dx = x - fqx, dy = y - fqy, dz = z - fqz;
        const float d2 = fmaf(dx, dx, fmaf(dy, dy, dz * dz));
        insert3(a0, a1, a2, ((u64)__float_as_uint(d2) << 32) | (unsigned)g);
      }
#pragma unroll
      for (int mask = 32; mask >= 1; mask >>= 1) {
        const u64 b0 = __shfl_xor(a0, mask, 64);
        const u64 b1 = __shfl_xor(a1, mask, 64);
        const u64 b2 = __shfl_xor(a2, mask, 64);
        merge3(a0, a1, a2, b0, b1, b2);
      }
      if (lane == 0) idw_out(b, fqn, fqx, fqy, fqz, a0, a1, a2, P1, F1, out);
    }
  }
}

extern "C" void kernel_launch(void* const* d_in, const int* in_sizes, int n_in,
                              void* d_out, int out_size, void* d_ws, size_t ws_size,
                              hipStream_t stream) {
  const float* pos1 = (const float*)d_in[0];
  const float* pos2 = (const float*)d_in[1];
  const float* flow1 = (const float*)d_in[2];
  float* out = (float*)d_out;

  // ws layout (16B-aligned sections)
  char* ws = (char*)d_ws;
  int* counts = (int*)ws;                                   // NCT ints
  unsigned* scanst = (unsigned*)(counts + NCT);             // 106 (pad 108)
  size_t offs_off = (size_t)(NCT + 108) * 4;                // 16B-aligned
  int* offs = (int*)(ws + offs_off);                        // NCT+1 ints
  size_t csr_off = (offs_off + ((size_t)NCT + 1) * 4 + 15) & ~(size_t)15;
  float4* csr = (float4*)(ws + csr_off);                    // BBNN float4

  k_zero<<<dim3((NZ4 + 255) / 256), dim3(256), 0, stream>>>((int4*)counts);
  k_count<<<dim3(BBNN / 256), dim3(256), 0, stream>>>(pos1, flow1, counts);
  k_scan<<<dim3(SB), dim3(256), 0, stream>>>(counts, offs, scanst);
  k_scat<<<dim3(BBNN / 256), dim3(256), 0, stream>>>(pos1, flow1, counts, offs, csr);
  k_query<<<dim3(BBNN * 32 / 256), dim3(256), 0, stream>>>(pos1, pos2, flow1, offs,
                                                           csr, out);
}